// Round 8
// baseline (71.642 us; speedup 1.0000x reference)
//
#include <hip/hip_runtime.h>
#include <hip/hip_bf16.h>

#define BATCH 8
#define NPT   2048
#define DIM   512
#define NTILE 16            // 2048/128 tiles per dim
#define NTRI  136           // 16*17/2 symmetric tiles per batch
#define NBLK  (NTRI * BATCH) // 1088

typedef __attribute__((ext_vector_type(8))) short bf16x8;
typedef __attribute__((ext_vector_type(4))) float f32x4;

// ---------------- workspace layout ----------------
#define OFF_SQ       16777216
#define OFF_MSUM     16842752
#define OFF_PARTIALS 16842784   // 1088 floats

// ---------------- kernel 1: normalize rows, emit bf16 + per-row |x|^2 ----------------
__global__ __launch_bounds__(256) void normalize_kernel(const float* __restrict__ emb,
                                                        __hip_bfloat16* __restrict__ xn,
                                                        float* __restrict__ sq) {
    const int wave = threadIdx.x >> 6;
    const int lane = threadIdx.x & 63;
    const int row  = blockIdx.x * 4 + wave;

    const float4* src = (const float4*)(emb + (size_t)row * DIM);
    float4 v0 = src[lane * 2 + 0];
    float4 v1 = src[lane * 2 + 1];

    float ss = v0.x*v0.x + v0.y*v0.y + v0.z*v0.z + v0.w*v0.w
             + v1.x*v1.x + v1.y*v1.y + v1.z*v1.z + v1.w*v1.w;
#pragma unroll
    for (int o = 32; o; o >>= 1) ss += __shfl_xor(ss, o);

    const float inv = 1.0f / fmaxf(sqrtf(ss), 1e-12f);

    float vals[8] = {v0.x, v0.y, v0.z, v0.w, v1.x, v1.y, v1.z, v1.w};
    unsigned int w[4];
    float s2 = 0.f;
#pragma unroll
    for (int i = 0; i < 4; i++) {
        __hip_bfloat16 h0 = __float2bfloat16(vals[2*i]   * inv);
        __hip_bfloat16 h1 = __float2bfloat16(vals[2*i+1] * inv);
        unsigned short u0 = *(unsigned short*)&h0;
        unsigned short u1 = *(unsigned short*)&h1;
        w[i] = (unsigned int)u0 | ((unsigned int)u1 << 16);
        float f0 = __bfloat162float(h0), f1 = __bfloat162float(h1);
        s2 += f0*f0 + f1*f1;
    }
    uint4 pk = {w[0], w[1], w[2], w[3]};
    *(uint4*)(xn + (size_t)row * DIM + lane * 8) = pk;

#pragma unroll
    for (int o = 32; o; o >>= 1) s2 += __shfl_xor(s2, o);
    if (lane == 0) sq[row] = s2;
}

// ---------------- kernel 2: per-batch mask sums ----------------
__global__ __launch_bounds__(256) void masksum_kernel(const float* __restrict__ mask,
                                                      float* __restrict__ msum) {
    const int b = blockIdx.x;
    float s = 0.f;
    for (int i = threadIdx.x; i < NPT; i += 256) s += mask[b * NPT + i];
#pragma unroll
    for (int o = 32; o; o >>= 1) s += __shfl_xor(s, o);
    __shared__ float ws[4];
    if ((threadIdx.x & 63) == 0) ws[threadIdx.x >> 6] = s;
    __syncthreads();
    if (threadIdx.x == 0) msum[b] = ws[0] + ws[1] + ws[2] + ws[3];
}

// ---------------- kernel 3: 128x128 tiles, BK=64, 8 phases, 1 barrier/phase ----------------
// 4 waves (2x2), per-wave 64x64, acc[4][4]=64 AGPR. Double-buffered 16KB regions.
// Phase: {16 ds_read (compiler lgkm-scheduled) | STAGE(p+1) | setprio(1) 32xMFMA
//         setprio(0) | vmcnt(0) | barrier}. vmcnt(0) sits AFTER the MFMA cluster, so
// stage loads have the whole cluster to fly; one barrier/phase serves both
// "next region visible" and the write-after-read fence (my ds_reads drained into
// MFMAs before I reach the barrier; STAGE(p+2) into this buffer comes after it).
// LDS swizzle (128B rows, 8 x 16B slots): read slot = (kk*4+lhi) ^ (llo&7);
// write side pre-swizzles source col by (lane&7)^(lane>>3). Bijective per row;
// every 8-lane group covers all 32 banks (same proof as the measured-0-conflict
// 64B-row variant of rounds 1-6).
__global__ __launch_bounds__(256) void gram_loss_kernel(const __hip_bfloat16* __restrict__ xn,
                                                        const float* __restrict__ sq,
                                                        const float* __restrict__ coords,
                                                        const float* __restrict__ mask,
                                                        float* __restrict__ partials) {
    __shared__ __align__(16) __hip_bfloat16 ldsA[2][128 * 64];   // 32 KB
    __shared__ __align__(16) __hip_bfloat16 ldsB[2][128 * 64];   // 32 KB
    __shared__ float s_sqr[128], s_sqc[128], s_mr[128], s_mc[128];
    __shared__ float s_cr[128][3], s_cc[128][3];
    __shared__ float s_wsum[4];

    // XCD-chunked: 1088 = 8 * 136; batch == XCD id -> 2 MB panel set per XCD L2
    const int bid = blockIdx.x;
    const int b   = bid & 7;
    int r = bid >> 3;
    int tm = 0;
    while (r >= NTILE - tm) { r -= NTILE - tm; tm++; }
    const int tn = tm + r;

    const int t    = threadIdx.x;
    const int wave = t >> 6, lane = t & 63;
    const int wr = wave >> 1, wc = wave & 1;      // 2 x 2 wave grid
    const int lhi = lane >> 4, llo = lane & 15;

    const size_t rowBaseA = (size_t)(b * NPT + tm * 128);
    const size_t rowBaseB = (size_t)(b * NPT + tn * 128);

    f32x4 acc[4][4];
#pragma unroll
    for (int i = 0; i < 4; i++)
#pragma unroll
        for (int j = 0; j < 4; j++) acc[i][j] = (f32x4){0.f, 0.f, 0.f, 0.f};

    // staging: region = 128 rows x 64 k bf16 (128 B/row) = 16 KB/side = 16 segs of
    // 1 KB (8 rows). Wave w covers segs 4w..4w+3 per side. Lane l: local row l>>3,
    // slot l&7; source col pre-swizzled: slot_src = (l&7) ^ (l>>3).
    const int lr   = lane >> 3;                      // 0..7
    const int swze = ((lane & 7) ^ lr) * 8;          // swizzled source col (elems)

    const __hip_bfloat16* srcA = xn + (rowBaseA + (size_t)(wave * 32 + lr)) * DIM + swze;
    const __hip_bfloat16* srcB = xn + (rowBaseB + (size_t)(wave * 32 + lr)) * DIM + swze;

#define STAGE_REGION(q_, bb_)                                                                   \
    {                                                                                           \
        const __hip_bfloat16* a_ = srcA + (q_) * 64;                                            \
        const __hip_bfloat16* b_ = srcB + (q_) * 64;                                            \
        _Pragma("unroll")                                                                       \
        for (int s_ = 0; s_ < 4; s_++) {                                                        \
            __builtin_amdgcn_global_load_lds(                                                   \
                (const __attribute__((address_space(1))) void*)(a_ + (size_t)s_ * 8 * DIM),     \
                (__attribute__((address_space(3))) void*)(&ldsA[bb_][(wave * 4 + s_) * 512]),   \
                16, 0, 0);                                                                      \
            __builtin_amdgcn_global_load_lds(                                                   \
                (const __attribute__((address_space(1))) void*)(b_ + (size_t)s_ * 8 * DIM),     \
                (__attribute__((address_space(3))) void*)(&ldsB[bb_][(wave * 4 + s_) * 512]),   \
                16, 0, 0);                                                                      \
        }                                                                                       \
    }

#define VMW(n_) asm volatile("s_waitcnt vmcnt(" #n_ ")" ::: "memory")

    // prologue: region 0 -> buf 0
    STAGE_REGION(0, 0);
    VMW(0);
    __builtin_amdgcn_s_barrier();

    // read offsets: byte = row*128 + ((kk*4+lhi)^(llo&7))*16
    const int llo7   = llo & 7;
    const int rsl0   = ((0 * 4 + lhi) ^ llo7) * 16;
    const int rsl1   = ((1 * 4 + lhi) ^ llo7) * 16;
    const int rowAby = (wr * 64 + llo) * 128;
    const int rowBby = (wc * 64 + llo) * 128;

#pragma unroll 1
    for (int p = 0; p < 8; p++) {
        const int cur = p & 1;
        const char* baA = (const char*)ldsA[cur];
        const char* baB = (const char*)ldsB[cur];
        bf16x8 af0[4], af1[4], bf0[4], bf1[4];
#pragma unroll
        for (int mi = 0; mi < 4; mi++) {
            af0[mi] = *(const bf16x8*)(baA + rowAby + mi * 2048 + rsl0);
            af1[mi] = *(const bf16x8*)(baA + rowAby + mi * 2048 + rsl1);
        }
#pragma unroll
        for (int ni = 0; ni < 4; ni++) {
            bf0[ni] = *(const bf16x8*)(baB + rowBby + ni * 2048 + rsl0);
            bf1[ni] = *(const bf16x8*)(baB + rowBby + ni * 2048 + rsl1);
        }
        if (p < 7) STAGE_REGION(p + 1, cur ^ 1);
        __builtin_amdgcn_s_setprio(1);
#pragma unroll
        for (int mi = 0; mi < 4; mi++)
#pragma unroll
            for (int ni = 0; ni < 4; ni++)
                acc[mi][ni] = __builtin_amdgcn_mfma_f32_16x16x32_bf16(af0[mi], bf0[ni],
                                                                      acc[mi][ni], 0, 0, 0);
#pragma unroll
        for (int mi = 0; mi < 4; mi++)
#pragma unroll
            for (int ni = 0; ni < 4; ni++)
                acc[mi][ni] = __builtin_amdgcn_mfma_f32_16x16x32_bf16(af1[mi], bf1[ni],
                                                                      acc[mi][ni], 0, 0, 0);
        __builtin_amdgcn_s_setprio(0);
        VMW(0);
        __builtin_amdgcn_s_barrier();
    }

#undef STAGE_REGION
#undef VMW

    // stage per-row/col metadata for the epilogue
    if (t < 128) {
        const int gi = b * NPT + tm * 128 + t;
        s_sqr[t]   = sq[gi];
        s_mr[t]    = mask[gi];
        s_cr[t][0] = coords[(size_t)gi * 3 + 0];
        s_cr[t][1] = coords[(size_t)gi * 3 + 1];
        s_cr[t][2] = coords[(size_t)gi * 3 + 2];
    } else {
        const int rr = t - 128;
        const int gi = b * NPT + tn * 128 + rr;
        s_sqc[rr]   = sq[gi];
        s_mc[rr]    = mask[gi];
        s_cc[rr][0] = coords[(size_t)gi * 3 + 0];
        s_cc[rr][1] = coords[(size_t)gi * 3 + 1];
        s_cc[rr][2] = coords[(size_t)gi * 3 + 2];
    }
    __syncthreads();

    // C/D layout: col = lane&15, row = (lane>>4)*4 + reg
    float lsum = 0.f;
#pragma unroll
    for (int mi = 0; mi < 4; mi++) {
#pragma unroll
        for (int j = 0; j < 4; j++) {
            const int rl  = wr * 64 + mi * 16 + lhi * 4 + j;
            const float sqr = s_sqr[rl];
            const float mr  = s_mr[rl];
            const float cx = s_cr[rl][0], cy = s_cr[rl][1], cz = s_cr[rl][2];
#pragma unroll
            for (int ni = 0; ni < 4; ni++) {
                const int cl = wc * 64 + ni * 16 + llo;
                const float g  = acc[mi][ni][j];
                float d2 = sqr + s_sqc[cl] - 2.f * g;
                d2 = fmaxf(d2, 0.f);
                const float de = sqrtf(d2);
                const float lo = fmaxf(de - 1.0f, 0.f);
                const float dx = cx - s_cc[cl][0];
                const float dy = cy - s_cc[cl][1];
                const float dz = cz - s_cc[cl][2];
                const float cd2 = dx*dx + dy*dy + dz*dz;
                const float wgt = (cd2 < 100.0f) ? mr * s_mc[cl] : 0.f;
                lsum += lo * wgt;
            }
        }
    }
    // off-diagonal tiles stand for both (tm,tn) and (tn,tm)
    if (tm != tn) lsum *= 2.0f;

#pragma unroll
    for (int o = 32; o; o >>= 1) lsum += __shfl_xor(lsum, o);
    if (lane == 0) s_wsum[wave] = lsum;
    __syncthreads();
    if (t == 0) {
        partials[bid] = s_wsum[0] + s_wsum[1] + s_wsum[2] + s_wsum[3];
    }
}

// ---------------- kernel 4: final deterministic reduce ----------------
__global__ __launch_bounds__(256) void finalize_kernel(const float* __restrict__ partials,
                                                       const float* __restrict__ msum,
                                                       float* __restrict__ out) {
    double s = 0.0;
    for (int i = threadIdx.x; i < NBLK; i += 256) s += (double)partials[i];
#pragma unroll
    for (int o = 32; o; o >>= 1) s += __shfl_xor(s, o);
    __shared__ double ws[4];
    if ((threadIdx.x & 63) == 0) ws[threadIdx.x >> 6] = s;
    __syncthreads();
    if (threadIdx.x == 0) {
        const double tot = ws[0] + ws[1] + ws[2] + ws[3];
        double valid = 0.0;
        for (int bb = 0; bb < BATCH; bb++) valid += (double)msum[bb] * (double)msum[bb];
        out[0] = (float)(tot / (valid + 1e-8));
    }
}

extern "C" void kernel_launch(void* const* d_in, const int* in_sizes, int n_in,
                              void* d_out, int out_size, void* d_ws, size_t ws_size,
                              hipStream_t stream) {
    const float* emb    = (const float*)d_in[0];
    const float* coords = (const float*)d_in[1];
    const float* mask   = (const float*)d_in[2];

    char* ws = (char*)d_ws;
    __hip_bfloat16* xn = (__hip_bfloat16*)ws;
    float* sq          = (float*)(ws + OFF_SQ);
    float* msum        = (float*)(ws + OFF_MSUM);
    float* partials    = (float*)(ws + OFF_PARTIALS);
    float* out         = (float*)d_out;

    normalize_kernel<<<dim3(BATCH * NPT / 4), dim3(256), 0, stream>>>(emb, xn, sq);
    masksum_kernel<<<dim3(BATCH), dim3(256), 0, stream>>>(mask, msum);
    gram_loss_kernel<<<dim3(NBLK), dim3(256), 0, stream>>>(xn, sq, coords, mask, partials);
    finalize_kernel<<<dim3(1), dim3(256), 0, stream>>>(partials, msum, out);
}

// Round 10
// 61.927 us; speedup vs baseline: 1.1569x; 1.1569x over previous
//
#include <hip/hip_runtime.h>
#include <hip/hip_bf16.h>

#define BATCH 8
#define NPT   2048
#define DIM   512
#define NTILE 16            // 2048/128 tiles per dim
#define NTRI  136           // 16*17/2 symmetric tiles per batch
#define NBLK  (NTRI * BATCH) // 1088

typedef __attribute__((ext_vector_type(8))) short bf16x8;
typedef __attribute__((ext_vector_type(4))) float f32x4;

// ---------------- workspace layout ----------------
#define OFF_SQ       16777216
#define OFF_MSUM     16842752
#define OFF_PARTIALS 16842784   // 1088 floats

// ---------------- kernel 1: normalize rows, emit bf16 + per-row |x|^2 ----------------
__global__ __launch_bounds__(256) void normalize_kernel(const float* __restrict__ emb,
                                                        __hip_bfloat16* __restrict__ xn,
                                                        float* __restrict__ sq) {
    const int wave = threadIdx.x >> 6;
    const int lane = threadIdx.x & 63;
    const int row  = blockIdx.x * 4 + wave;

    const float4* src = (const float4*)(emb + (size_t)row * DIM);
    float4 v0 = src[lane * 2 + 0];
    float4 v1 = src[lane * 2 + 1];

    float ss = v0.x*v0.x + v0.y*v0.y + v0.z*v0.z + v0.w*v0.w
             + v1.x*v1.x + v1.y*v1.y + v1.z*v1.z + v1.w*v1.w;
#pragma unroll
    for (int o = 32; o; o >>= 1) ss += __shfl_xor(ss, o);

    const float inv = 1.0f / fmaxf(sqrtf(ss), 1e-12f);

    float vals[8] = {v0.x, v0.y, v0.z, v0.w, v1.x, v1.y, v1.z, v1.w};
    unsigned int w[4];
    float s2 = 0.f;
#pragma unroll
    for (int i = 0; i < 4; i++) {
        __hip_bfloat16 h0 = __float2bfloat16(vals[2*i]   * inv);
        __hip_bfloat16 h1 = __float2bfloat16(vals[2*i+1] * inv);
        unsigned short u0 = *(unsigned short*)&h0;
        unsigned short u1 = *(unsigned short*)&h1;
        w[i] = (unsigned int)u0 | ((unsigned int)u1 << 16);
        float f0 = __bfloat162float(h0), f1 = __bfloat162float(h1);
        s2 += f0*f0 + f1*f1;
    }
    uint4 pk = {w[0], w[1], w[2], w[3]};
    *(uint4*)(xn + (size_t)row * DIM + lane * 8) = pk;

#pragma unroll
    for (int o = 32; o; o >>= 1) s2 += __shfl_xor(s2, o);
    if (lane == 0) sq[row] = s2;
}

// ---------------- kernel 2: per-batch mask sums ----------------
__global__ __launch_bounds__(256) void masksum_kernel(const float* __restrict__ mask,
                                                      float* __restrict__ msum) {
    const int b = blockIdx.x;
    float s = 0.f;
    for (int i = threadIdx.x; i < NPT; i += 256) s += mask[b * NPT + i];
#pragma unroll
    for (int o = 32; o; o >>= 1) s += __shfl_xor(s, o);
    __shared__ float ws[4];
    if ((threadIdx.x & 63) == 0) ws[threadIdx.x >> 6] = s;
    __syncthreads();
    if (threadIdx.x == 0) msum[b] = ws[0] + ws[1] + ws[2] + ws[3];
}

// ---------------- kernel 3: 128x128 tiles, 8 waves x (64x32), BK=32, high occupancy ----------------
// OCCUPANCY ROUND (fixed): round 8's staging base was wave*1024 elems, but wave w's
// 16 rows live at 16w * 32 elems/row = wave*512 elems -> half of each region was
// never written (0xAA poison -> inf). One-line fix; all else identical.
// acc[4][2] = 32 AGPR, frags 24, misc ~30 -> ~90 unified; __launch_bounds__(512,4)
// caps at 128 -> 4 waves/SIMD (16 waves/CU, 2 blocks/CU). Double prior TLP.
// BK=32 double-buffer; round-1's measured-0-conflict swizzle (64B rows).
__global__ __launch_bounds__(512, 4) void gram_loss_kernel(const __hip_bfloat16* __restrict__ xn,
                                                           const float* __restrict__ sq,
                                                           const float* __restrict__ coords,
                                                           const float* __restrict__ mask,
                                                           float* __restrict__ partials) {
    __shared__ __align__(16) __hip_bfloat16 ldsA[2][128 * 32];   // 16 KB
    __shared__ __align__(16) __hip_bfloat16 ldsB[2][128 * 32];   // 16 KB
    __shared__ float s_sqr[128], s_sqc[128], s_mr[128], s_mc[128];
    __shared__ float s_cr[128][3], s_cc[128][3];
    __shared__ float s_wsum[8];

    // XCD-chunked: 1088 = 8 * 136; batch == XCD id -> 2 MB panel set per XCD L2
    const int bid = blockIdx.x;
    const int b   = bid & 7;
    int r = bid >> 3;
    int tm = 0;
    while (r >= NTILE - tm) { r -= NTILE - tm; tm++; }
    const int tn = tm + r;

    const int t    = threadIdx.x;
    const int wave = t >> 6, lane = t & 63;
    const int wr = wave >> 2, wc = wave & 3;      // 2 x 4 wave grid: 64-row x 32-col tiles
    const int lhi = lane >> 4, llo = lane & 15;

    const size_t rowBaseA = (size_t)(b * NPT + tm * 128);
    const size_t rowBaseB = (size_t)(b * NPT + tn * 128);

    f32x4 acc[4][2];
#pragma unroll
    for (int i = 0; i < 4; i++)
#pragma unroll
        for (int j = 0; j < 2; j++) acc[i][j] = (f32x4){0.f, 0.f, 0.f, 0.f};

    // staging: region = 128 rows x 32 k bf16 = 8 KB/side = 512 lanes x 16 B.
    // wave w covers rows [w*16, w*16+16): lane l -> row w*16 + (l>>2), slot l&3.
    // source col pre-swizzled: src_slot = (l&3) ^ ((l>>3)&3); read applies same XOR.
    const int srow = lane >> 2;
    const int scol = ((lane & 3) ^ ((lane >> 3) & 3)) * 8;

    const __hip_bfloat16* srcA = xn + (rowBaseA + (size_t)(wave * 16 + srow)) * DIM + scol;
    const __hip_bfloat16* srcB = xn + (rowBaseB + (size_t)(wave * 16 + srow)) * DIM + scol;
    const int segoff = wave * 512;   // elem offset of this wave's 16-row segment (16*32 elems)

#define STAGE_REGION(q_, bb_)                                                                   \
    {                                                                                           \
        __builtin_amdgcn_global_load_lds(                                                       \
            (const __attribute__((address_space(1))) void*)(srcA + (q_) * 32),                  \
            (__attribute__((address_space(3))) void*)(&ldsA[bb_][segoff]), 16, 0, 0);           \
        __builtin_amdgcn_global_load_lds(                                                       \
            (const __attribute__((address_space(1))) void*)(srcB + (q_) * 32),                  \
            (__attribute__((address_space(3))) void*)(&ldsB[bb_][segoff]), 16, 0, 0);           \
    }

#define VMW(n_) asm volatile("s_waitcnt vmcnt(" #n_ ")" ::: "memory")

    // prologue: region 0 -> buf 0
    STAGE_REGION(0, 0);
    VMW(0);
    __builtin_amdgcn_s_barrier();

    const int rsl    = (lhi ^ ((llo >> 1) & 3)) * 16;   // swizzled 16B slot in 64B row
    const int rowAby = (wr * 64 + llo) * 64;            // A rows: wr*64 + mi*16 + llo
    const int rowBby = (wc * 32 + llo) * 64;            // B rows: wc*32 + ni*16 + llo

#pragma unroll 1
    for (int p = 0; p < 16; p++) {
        const int cur = p & 1;
        const char* baA = (const char*)ldsA[cur];
        const char* baB = (const char*)ldsB[cur];
        bf16x8 af[4], bfr[2];
#pragma unroll
        for (int mi = 0; mi < 4; mi++)
            af[mi] = *(const bf16x8*)(baA + rowAby + mi * 1024 + rsl);
#pragma unroll
        for (int ni = 0; ni < 2; ni++)
            bfr[ni] = *(const bf16x8*)(baB + rowBby + ni * 1024 + rsl);
        if (p < 15) STAGE_REGION(p + 1, cur ^ 1);
        __builtin_amdgcn_s_setprio(1);
#pragma unroll
        for (int mi = 0; mi < 4; mi++)
#pragma unroll
            for (int ni = 0; ni < 2; ni++)
                acc[mi][ni] = __builtin_amdgcn_mfma_f32_16x16x32_bf16(af[mi], bfr[ni],
                                                                      acc[mi][ni], 0, 0, 0);
        __builtin_amdgcn_s_setprio(0);
        VMW(0);
        __builtin_amdgcn_s_barrier();
    }

#undef STAGE_REGION
#undef VMW

    // stage per-row/col metadata for the epilogue
    if (t < 128) {
        const int gi = b * NPT + tm * 128 + t;
        s_sqr[t]   = sq[gi];
        s_mr[t]    = mask[gi];
        s_cr[t][0] = coords[(size_t)gi * 3 + 0];
        s_cr[t][1] = coords[(size_t)gi * 3 + 1];
        s_cr[t][2] = coords[(size_t)gi * 3 + 2];
    } else if (t < 256) {
        const int rr = t - 128;
        const int gi = b * NPT + tn * 128 + rr;
        s_sqc[rr]   = sq[gi];
        s_mc[rr]    = mask[gi];
        s_cc[rr][0] = coords[(size_t)gi * 3 + 0];
        s_cc[rr][1] = coords[(size_t)gi * 3 + 1];
        s_cc[rr][2] = coords[(size_t)gi * 3 + 2];
    }
    __syncthreads();

    // C/D layout: col = lane&15, row = (lane>>4)*4 + reg
    float lsum = 0.f;
#pragma unroll
    for (int mi = 0; mi < 4; mi++) {
#pragma unroll
        for (int j = 0; j < 4; j++) {
            const int rl  = wr * 64 + mi * 16 + lhi * 4 + j;
            const float sqr = s_sqr[rl];
            const float mr  = s_mr[rl];
            const float cx = s_cr[rl][0], cy = s_cr[rl][1], cz = s_cr[rl][2];
#pragma unroll
            for (int ni = 0; ni < 2; ni++) {
                const int cl = wc * 32 + ni * 16 + llo;
                const float g  = acc[mi][ni][j];
                float d2 = sqr + s_sqc[cl] - 2.f * g;
                d2 = fmaxf(d2, 0.f);
                const float de = sqrtf(d2);
                const float lo = fmaxf(de - 1.0f, 0.f);
                const float dx = cx - s_cc[cl][0];
                const float dy = cy - s_cc[cl][1];
                const float dz = cz - s_cc[cl][2];
                const float cd2 = dx*dx + dy*dy + dz*dz;
                const float wgt = (cd2 < 100.0f) ? mr * s_mc[cl] : 0.f;
                lsum += lo * wgt;
            }
        }
    }
    // off-diagonal tiles stand for both (tm,tn) and (tn,tm)
    if (tm != tn) lsum *= 2.0f;

#pragma unroll
    for (int o = 32; o; o >>= 1) lsum += __shfl_xor(lsum, o);
    if (lane == 0) s_wsum[wave] = lsum;
    __syncthreads();
    if (t == 0) {
        float bs = 0.f;
#pragma unroll
        for (int i = 0; i < 8; i++) bs += s_wsum[i];
        partials[bid] = bs;
    }
}

// ---------------- kernel 4: final deterministic reduce ----------------
__global__ __launch_bounds__(256) void finalize_kernel(const float* __restrict__ partials,
                                                       const float* __restrict__ msum,
                                                       float* __restrict__ out) {
    double s = 0.0;
    for (int i = threadIdx.x; i < NBLK; i += 256) s += (double)partials[i];
#pragma unroll
    for (int o = 32; o; o >>= 1) s += __shfl_xor(s, o);
    __shared__ double ws[4];
    if ((threadIdx.x & 63) == 0) ws[threadIdx.x >> 6] = s;
    __syncthreads();
    if (threadIdx.x == 0) {
        const double tot = ws[0] + ws[1] + ws[2] + ws[3];
        double valid = 0.0;
        for (int bb = 0; bb < BATCH; bb++) valid += (double)msum[bb] * (double)msum[bb];
        out[0] = (float)(tot / (valid + 1e-8));
    }
}

extern "C" void kernel_launch(void* const* d_in, const int* in_sizes, int n_in,
                              void* d_out, int out_size, void* d_ws, size_t ws_size,
                              hipStream_t stream) {
    const float* emb    = (const float*)d_in[0];
    const float* coords = (const float*)d_in[1];
    const float* mask   = (const float*)d_in[2];

    char* ws = (char*)d_ws;
    __hip_bfloat16* xn = (__hip_bfloat16*)ws;
    float* sq          = (float*)(ws + OFF_SQ);
    float* msum        = (float*)(ws + OFF_MSUM);
    float* partials    = (float*)(ws + OFF_PARTIALS);
    float* out         = (float*)d_out;

    normalize_kernel<<<dim3(BATCH * NPT / 4), dim3(256), 0, stream>>>(emb, xn, sq);
    masksum_kernel<<<dim3(BATCH), dim3(256), 0, stream>>>(mask, msum);
    gram_loss_kernel<<<dim3(NBLK), dim3(512), 0, stream>>>(xn, sq, coords, mask, partials);
    finalize_kernel<<<dim3(1), dim3(256), 0, stream>>>(partials, msum, out);
}

// Round 12
// 56.199 us; speedup vs baseline: 1.2748x; 1.1019x over previous
//
#include <hip/hip_runtime.h>
#include <hip/hip_bf16.h>

#define BATCH 8
#define NPT   2048
#define DIM   512
#define NTILE 16            // 2048/128 tiles per dim
#define NTRI  136           // 16*17/2 symmetric tiles per batch
#define NBLK  (NTRI * BATCH) // 1088

typedef __attribute__((ext_vector_type(4))) float f32x4;

// ---------------- workspace layout ----------------
// xn (fp8)  : 8,388,608 B at 0
#define OFF_SQ       16777216
#define OFF_MSUM     16842752
#define OFF_PARTIALS 16842784   // 1088 floats

// ---------------- kernel 1: normalize rows, emit fp8 e4m3 + per-row |x_q|^2 ----------------
// fp8 via HW builtins (v_cvt_pk_fp8_f32 / v_cvt_f32_fp8 — OCP e4m3 on gfx950).
// sq computed from the DEQUANTIZED values so d2 = |x^-y^|^2 >= 0 exactly.
// NOTE: cvt_f32_fp8's byte selector must be a LITERAL (compile error w/ loop var).
__global__ __launch_bounds__(256) void normalize_kernel(const float* __restrict__ emb,
                                                        unsigned char* __restrict__ xn,
                                                        float* __restrict__ sq) {
    const int wave = threadIdx.x >> 6;
    const int lane = threadIdx.x & 63;
    const int row  = blockIdx.x * 4 + wave;

    const float4* src = (const float4*)(emb + (size_t)row * DIM);
    float4 v0 = src[lane * 2 + 0];
    float4 v1 = src[lane * 2 + 1];

    float ss = v0.x*v0.x + v0.y*v0.y + v0.z*v0.z + v0.w*v0.w
             + v1.x*v1.x + v1.y*v1.y + v1.z*v1.z + v1.w*v1.w;
#pragma unroll
    for (int o = 32; o; o >>= 1) ss += __shfl_xor(ss, o);

    const float inv = 1.0f / fmaxf(sqrtf(ss), 1e-12f);

    const float f0 = v0.x*inv, f1 = v0.y*inv, f2 = v0.z*inv, f3 = v0.w*inv;
    const float f4 = v1.x*inv, f5 = v1.y*inv, f6 = v1.z*inv, f7 = v1.w*inv;

    int lo = __builtin_amdgcn_cvt_pk_fp8_f32(f0, f1, 0, 0);
    lo     = __builtin_amdgcn_cvt_pk_fp8_f32(f2, f3, lo, 1);
    int hi = __builtin_amdgcn_cvt_pk_fp8_f32(f4, f5, 0, 0);
    hi     = __builtin_amdgcn_cvt_pk_fp8_f32(f6, f7, hi, 1);

    float s2 = 0.f;
    {
        float a;
        a = __builtin_amdgcn_cvt_f32_fp8(lo, 0); s2 += a * a;
        a = __builtin_amdgcn_cvt_f32_fp8(lo, 1); s2 += a * a;
        a = __builtin_amdgcn_cvt_f32_fp8(lo, 2); s2 += a * a;
        a = __builtin_amdgcn_cvt_f32_fp8(lo, 3); s2 += a * a;
        a = __builtin_amdgcn_cvt_f32_fp8(hi, 0); s2 += a * a;
        a = __builtin_amdgcn_cvt_f32_fp8(hi, 1); s2 += a * a;
        a = __builtin_amdgcn_cvt_f32_fp8(hi, 2); s2 += a * a;
        a = __builtin_amdgcn_cvt_f32_fp8(hi, 3); s2 += a * a;
    }

    uint2 pk; pk.x = (unsigned)lo; pk.y = (unsigned)hi;
    *(uint2*)(xn + (size_t)row * DIM + lane * 8) = pk;

#pragma unroll
    for (int o = 32; o; o >>= 1) s2 += __shfl_xor(s2, o);
    if (lane == 0) sq[row] = s2;
}

// ---------------- kernel 2: per-batch mask sums ----------------
__global__ __launch_bounds__(256) void masksum_kernel(const float* __restrict__ mask,
                                                      float* __restrict__ msum) {
    const int b = blockIdx.x;
    float s = 0.f;
    for (int i = threadIdx.x; i < NPT; i += 256) s += mask[b * NPT + i];
#pragma unroll
    for (int o = 32; o; o >>= 1) s += __shfl_xor(s, o);
    __shared__ float ws[4];
    if ((threadIdx.x & 63) == 0) ws[threadIdx.x >> 6] = s;
    __syncthreads();
    if (threadIdx.x == 0) msum[b] = ws[0] + ws[1] + ws[2] + ws[3];
}

// ---------------- kernel 3: fp8 Gram, 128x128 tiles, 8 waves x (64x32), BK=32 ----------------
// mfma_f32_16x16x32_fp8_fp8 (bf16 rate, HALF the bytes): per wave per phase
// 6 x ds_read_b64 = 3 KB for 8 MFMA -> 43 FLOP/B (was 21 with bf16).
// 4-region rotation (4 KB/side/region), stage 3 ahead, counted VMW(2),
// 1 barrier/phase (write-after-read safe: STAGE(p+3) issued after top barrier
// of phase p; region (p-1)&3's reads were issued in phase p-1 body).
// Staging: 1 gload_lds/thread/region; waves 0-3 stage A, 4-7 stage B.
// fp8 swizzle (32-B rows, b64 reads): phys octet = g ^ ((row>>2)&2) ->
// per 16-lane group 8 bank-pairs x 2 lanes = 2-way = free; XOR is even so the
// 16-B staged chunk keeps source byte order. A and B read identically, so any
// within-fragment k-permutation of the fp8 operand layout cancels in the Gram.
__global__ __launch_bounds__(512, 4) void gram_loss_kernel(const unsigned char* __restrict__ xn,
                                                           const float* __restrict__ sq,
                                                           const float* __restrict__ coords,
                                                           const float* __restrict__ mask,
                                                           float* __restrict__ partials) {
    __shared__ __align__(16) unsigned char ldsA[4][4096];   // 16 KB
    __shared__ __align__(16) unsigned char ldsB[4][4096];   // 16 KB
    __shared__ float s_sqr[128], s_sqc[128], s_mr[128], s_mc[128];
    __shared__ float s_cr[128][3], s_cc[128][3];
    __shared__ float s_wsum[8];

    // XCD-chunked: 1088 = 8 * 136; batch == XCD id -> ~1 MB panel set per XCD L2
    const int bid = blockIdx.x;
    const int b   = bid & 7;
    int r = bid >> 3;
    int tm = 0;
    while (r >= NTILE - tm) { r -= NTILE - tm; tm++; }
    const int tn = tm + r;

    const int t    = threadIdx.x;
    const int wave = t >> 6, lane = t & 63;
    const int wr = wave >> 2, wc = wave & 3;      // 2 x 4 wave grid: 64-row x 32-col tiles
    const int lhi = lane >> 4, llo = lane & 15;

    const size_t rowBaseA = (size_t)(b * NPT + tm * 128);
    const size_t rowBaseB = (size_t)(b * NPT + tn * 128);

    f32x4 acc[4][2];
#pragma unroll
    for (int i = 0; i < 4; i++)
#pragma unroll
        for (int j = 0; j < 2; j++) acc[i][j] = (f32x4){0.f, 0.f, 0.f, 0.f};

    // staging: region = 128 rows x 32 k fp8 = 4 KB/side = 256 lanes x 16 B.
    // thread t: side = t>=256; l = t&255; row = l>>1; covers phys octets {2(l&1), 2(l&1)+1}.
    // source col pre-swizzled: byte = ((2*(l&1)) ^ ((l>>3)&2)) * 8.
    const int ls    = t & 255;
    const int side  = t >> 8;                 // 0 = A (waves 0-3), 1 = B (waves 4-7)
    const int srow  = ls >> 1;
    const int scolB = ((2 * (ls & 1)) ^ ((ls >> 3) & 2)) * 8;

    const unsigned char* gsrc = xn + ((side ? rowBaseB : rowBaseA) + (size_t)srow) * DIM + scolB;
    const int dstoff = ls * 16;

#define STAGE_REGION(q_)                                                                        \
    {                                                                                           \
        unsigned char* d_ = (side ? &ldsB[(q_) & 3][0] : &ldsA[(q_) & 3][0]) + dstoff;          \
        __builtin_amdgcn_global_load_lds(                                                       \
            (const __attribute__((address_space(1))) void*)(gsrc + (q_) * 32),                  \
            (__attribute__((address_space(3))) void*)d_, 16, 0, 0);                             \
    }

#define VMW(n_) asm volatile("s_waitcnt vmcnt(" #n_ ")" ::: "memory")

    // prologue: regions 0,1,2 in flight (1 load/thread each)
    STAGE_REGION(0);
    STAGE_REGION(1);
    STAGE_REGION(2);

    // read: byte = row*32 + (g ^ ((row>>2)&2))*8 ; row>>2 parity from llo only
    const int koff   = (lhi ^ ((llo >> 2) & 2)) * 8;
    const int rowAby = (wr * 64 + llo) * 32;   // + mi*512
    const int rowBby = (wc * 32 + llo) * 32;   // + ni*512

#pragma unroll 1
    for (int p = 0; p < 16; p++) {
        if (p < 14)      { VMW(2); }
        else if (p == 14){ VMW(1); }
        else             { VMW(0); }
        __builtin_amdgcn_s_barrier();

        const unsigned char* baA = &ldsA[p & 3][0];
        const unsigned char* baB = &ldsB[p & 3][0];
        long af[4], bfr[2];
#pragma unroll
        for (int mi = 0; mi < 4; mi++)
            af[mi] = *(const long*)(baA + rowAby + mi * 512 + koff);
#pragma unroll
        for (int ni = 0; ni < 2; ni++)
            bfr[ni] = *(const long*)(baB + rowBby + ni * 512 + koff);

        if (p < 13) STAGE_REGION(p + 3);

        __builtin_amdgcn_s_setprio(1);
#pragma unroll
        for (int mi = 0; mi < 4; mi++)
#pragma unroll
            for (int ni = 0; ni < 2; ni++)
                acc[mi][ni] = __builtin_amdgcn_mfma_f32_16x16x32_fp8_fp8(af[mi], bfr[ni],
                                                                         acc[mi][ni], 0, 0, 0);
        __builtin_amdgcn_s_setprio(0);
    }

#undef STAGE_REGION
#undef VMW

    // stage per-row/col metadata for the epilogue
    __syncthreads();
    if (t < 128) {
        const int gi = b * NPT + tm * 128 + t;
        s_sqr[t]   = sq[gi];
        s_mr[t]    = mask[gi];
        s_cr[t][0] = coords[(size_t)gi * 3 + 0];
        s_cr[t][1] = coords[(size_t)gi * 3 + 1];
        s_cr[t][2] = coords[(size_t)gi * 3 + 2];
    } else if (t < 256) {
        const int rr = t - 128;
        const int gi = b * NPT + tn * 128 + rr;
        s_sqc[rr]   = sq[gi];
        s_mc[rr]    = mask[gi];
        s_cc[rr][0] = coords[(size_t)gi * 3 + 0];
        s_cc[rr][1] = coords[(size_t)gi * 3 + 1];
        s_cc[rr][2] = coords[(size_t)gi * 3 + 2];
    }
    __syncthreads();

    // C/D layout: col = lane&15, row = (lane>>4)*4 + reg
    float lsum = 0.f;
#pragma unroll
    for (int mi = 0; mi < 4; mi++) {
#pragma unroll
        for (int j = 0; j < 4; j++) {
            const int rl  = wr * 64 + mi * 16 + lhi * 4 + j;
            const float sqr = s_sqr[rl];
            const float mr  = s_mr[rl];
            const float cx = s_cr[rl][0], cy = s_cr[rl][1], cz = s_cr[rl][2];
#pragma unroll
            for (int ni = 0; ni < 2; ni++) {
                const int cl = wc * 32 + ni * 16 + llo;
                const float g  = acc[mi][ni][j];
                float d2 = sqr + s_sqc[cl] - 2.f * g;
                d2 = fmaxf(d2, 0.f);
                const float de = sqrtf(d2);
                const float lo = fmaxf(de - 1.0f, 0.f);
                const float dx = cx - s_cc[cl][0];
                const float dy = cy - s_cc[cl][1];
                const float dz = cz - s_cc[cl][2];
                const float cd2 = dx*dx + dy*dy + dz*dz;
                const float wgt = (cd2 < 100.0f) ? mr * s_mc[cl] : 0.f;
                lsum += lo * wgt;
            }
        }
    }
    // off-diagonal tiles stand for both (tm,tn) and (tn,tm)
    if (tm != tn) lsum *= 2.0f;

#pragma unroll
    for (int o = 32; o; o >>= 1) lsum += __shfl_xor(lsum, o);
    if (lane == 0) s_wsum[wave] = lsum;
    __syncthreads();
    if (t == 0) {
        float bs = 0.f;
#pragma unroll
        for (int i = 0; i < 8; i++) bs += s_wsum[i];
        partials[bid] = bs;
    }
}

// ---------------- kernel 4: final deterministic reduce ----------------
__global__ __launch_bounds__(256) void finalize_kernel(const float* __restrict__ partials,
                                                       const float* __restrict__ msum,
                                                       float* __restrict__ out) {
    double s = 0.0;
    for (int i = threadIdx.x; i < NBLK; i += 256) s += (double)partials[i];
#pragma unroll
    for (int o = 32; o; o >>= 1) s += __shfl_xor(s, o);
    __shared__ double ws[4];
    if ((threadIdx.x & 63) == 0) ws[threadIdx.x >> 6] = s;
    __syncthreads();
    if (threadIdx.x == 0) {
        const double tot = ws[0] + ws[1] + ws[2] + ws[3];
        double valid = 0.0;
        for (int bb = 0; bb < BATCH; bb++) valid += (double)msum[bb] * (double)msum[bb];
        out[0] = (float)(tot / (valid + 1e-8));
    }
}

extern "C" void kernel_launch(void* const* d_in, const int* in_sizes, int n_in,
                              void* d_out, int out_size, void* d_ws, size_t ws_size,
                              hipStream_t stream) {
    const float* emb    = (const float*)d_in[0];
    const float* coords = (const float*)d_in[1];
    const float* mask   = (const float*)d_in[2];

    char* ws = (char*)d_ws;
    unsigned char* xn  = (unsigned char*)ws;
    float* sq          = (float*)(ws + OFF_SQ);
    float* msum        = (float*)(ws + OFF_MSUM);
    float* partials    = (float*)(ws + OFF_PARTIALS);
    float* out         = (float*)d_out;

    normalize_kernel<<<dim3(BATCH * NPT / 4), dim3(256), 0, stream>>>(emb, xn, sq);
    masksum_kernel<<<dim3(BATCH), dim3(256), 0, stream>>>(mask, msum);
    gram_loss_kernel<<<dim3(NBLK), dim3(512), 0, stream>>>(xn, sq, coords, mask, partials);
    finalize_kernel<<<dim3(1), dim3(256), 0, stream>>>(partials, msum, out);
}